// Round 8
// baseline (110.426 us; speedup 1.0000x reference)
//
#include <hip/hip_runtime.h>

// RNN: h_t = tanh(x_t*w_ih + b_ih + b_hh + W_hh h_{t-1});  out = h_T . w_fc + b_fc
// B=4096, T=512, I=1, H=16, O=1.
//
// Round 7 = round-2 layout (verified) + round-5 asm DPP fusion (verified):
//   32 lanes per batch -> 131072 threads -> 2 waves/SIMD (TLP fills the
//   serial-chain bubbles that cap the 16-lane layout at ~42us), with the 7
//   h-rotations fused into v_mul/fmac_f32_dpp (no standalone DPP movs).
//   Row-even lane l: output o=l, rotations 0..7, owns x/bias term.
//   Row-odd  lane l: output o=(l+8)&15, same rotations (= offsets 8..15 of o),
//   NO x/bias (gated to 0 at setup). Masked ror8 DPP realigns odd-row partials
//   to index (lane&15); permlane16_swap+add completes the 16-term dot in every
//   lane; all lanes tanh -> plain h[lane&15] invariant restored for free.
// Direction-proofing: weights gathered by pushing the lane index through
// __builtin_amdgcn_update_dpp with ctrl 0x120+r — the same ctrl the asm's
// row_ror:r encodes — so HW rotation convention cancels out.
// tanh prescale 2*log2(e) folded into weights/biases:
//   tanh(s) = 1 - 2/(exp2(s')+1), s' = 2*log2(e)*s.

constexpr int T_STEPS = 512;
constexpr float C2LE = 2.8853900817779268f; // 2*log2(e)

#define DPP_CTRL_ROR(r) (0x120 + (r))
#define DPP_ROR_IDX(r, src) __builtin_amdgcn_update_dpp(0, (src), DPP_CTRL_ROR(r), 0xF, 0xF, false)
// ror8 applied to 16-lane rows 1,3 only (row_mask 0xA); masked rows keep old.
#define DPP_ROR8_ODDROWS(old_, src_) __builtin_amdgcn_update_dpp((old_), (src_), 0x128, 0xA, 0xF, false)

__device__ __forceinline__ float xor16_sum(float p) {
#if __has_builtin(__builtin_amdgcn_permlane16_swap)
    // a+b == p[lane] + p[lane^16] in every lane (VALU pipe, no DS).
    auto pr = __builtin_amdgcn_permlane16_swap((unsigned)__float_as_int(p),
                                               (unsigned)__float_as_int(p),
                                               false, false);
    return __int_as_float((int)pr[0]) + __int_as_float((int)pr[1]);
#else
    int o_ = __builtin_amdgcn_ds_swizzle(__float_as_int(p), 0x401F);
    return p + __int_as_float(o_);
#endif
}

__global__ __launch_bounds__(256) void rnn_fused(
    const float* __restrict__ x,
    const float* __restrict__ w_ih,
    const float* __restrict__ w_hh,
    const float* __restrict__ b_ih,
    const float* __restrict__ b_hh,
    const float* __restrict__ w_fc,
    const float* __restrict__ b_fc,
    float* __restrict__ out)
{
    const int tid     = blockIdx.x * blockDim.x + threadIdx.x;
    const int b       = tid >> 5;                 // batch element (32 lanes each)
    const int lane    = threadIdx.x & 63;         // wave lane
    const int l       = lane & 15;                // position within 16-lane row
    const int row_odd = (lane >> 4) & 1;          // odd row of the batch's pair
    const int o       = (l + (row_odd << 3)) & 15;// output unit this lane accumulates

    // x/bias owned by the even row ONLY (round-2 verified fix).
    const float wihc  = row_odd ? 0.0f : w_ih[o] * C2LE;
    const float biasc = row_odd ? 0.0f : (b_ih[o] + b_hh[o]) * C2LE;

    // Direction-proof weight gather through the same DPP ctrl the asm uses.
    float wr[8];
    {
        const int base = o << 4;                  // w_hh row o (H x H row-major)
        wr[0] = w_hh[base + l] * C2LE;            // r=0: own value h[l]
        #define WSETUP(r) { int s_ = DPP_ROR_IDX(r, l); wr[r] = w_hh[base + s_] * C2LE; }
        WSETUP(1) WSETUP(2) WSETUP(3) WSETUP(4) WSETUP(5) WSETUP(6) WSETUP(7)
        #undef WSETUP
    }
    const float w0 = wr[0], w1 = wr[1], w2 = wr[2], w3 = wr[3];
    const float w4 = wr[4], w5 = wr[5], w6 = wr[6], w7 = wr[7];

    const float* xb = x + ((size_t)b << 9);       // x[b,:,0], 512 floats, 16B aligned
    float h = 0.0f;

    // One timestep. p0/p1 alternate as accumulators (same-acc ops 2 insts =
    // 4 cyc apart). s_nop 1 covers the VALU-write(h) -> DPP-read hazard that
    // is opaque to the compiler inside the asm block.
    #define STEP(xval) {                                                       \
        float p0 = fmaf((xval), wihc, biasc);                                  \
        p0 = fmaf(h, w0, p0);                                                  \
        float p1;                                                              \
        asm volatile(                                                          \
          "s_nop 1\n\t"                                                        \
          "v_mul_f32_dpp  %0, %2, %3 row_ror:1 row_mask:0xf bank_mask:0xf\n\t" \
          "v_fmac_f32_dpp %1, %2, %4 row_ror:2 row_mask:0xf bank_mask:0xf\n\t" \
          "v_fmac_f32_dpp %0, %2, %5 row_ror:3 row_mask:0xf bank_mask:0xf\n\t" \
          "v_fmac_f32_dpp %1, %2, %6 row_ror:4 row_mask:0xf bank_mask:0xf\n\t" \
          "v_fmac_f32_dpp %0, %2, %7 row_ror:5 row_mask:0xf bank_mask:0xf\n\t" \
          "v_fmac_f32_dpp %1, %2, %8 row_ror:6 row_mask:0xf bank_mask:0xf\n\t" \
          "v_fmac_f32_dpp %0, %2, %9 row_ror:7 row_mask:0xf bank_mask:0xf"     \
          : "=&v"(p1), "+v"(p0)                                                \
          : "v"(h), "v"(w1), "v"(w2), "v"(w3), "v"(w4), "v"(w5), "v"(w6),      \
            "v"(w7));                                                          \
        float P = p0 + p1;                                                     \
        P = __int_as_float(DPP_ROR8_ODDROWS(__float_as_int(P),                 \
                                            __float_as_int(P)));               \
        const float s_ = xor16_sum(P);    /* full scaled dot, every lane */    \
        const float e_ = __builtin_amdgcn_exp2f(s_);                           \
        const float rc = __builtin_amdgcn_rcpf(e_ + 1.0f);                     \
        h = fmaf(-2.0f, rc, 1.0f);        /* every lane: h[lane&15] */         \
    }

    // 8 steps/iter; next x block prefetched as 2x float4 (L1-resident,
    // 32 lanes same address -> broadcast).
    float4 cur0 = *reinterpret_cast<const float4*>(xb);
    float4 cur1 = *reinterpret_cast<const float4*>(xb + 4);
    #pragma unroll 1
    for (int tb = 0; tb < T_STEPS; tb += 8) {
        const int nxt = (tb + 8 < T_STEPS) ? (tb + 8) : 0;  // last iter: dummy
        const float4 n0 = *reinterpret_cast<const float4*>(xb + nxt);
        const float4 n1 = *reinterpret_cast<const float4*>(xb + nxt + 4);
        STEP(cur0.x) STEP(cur0.y) STEP(cur0.z) STEP(cur0.w)
        STEP(cur1.x) STEP(cur1.y) STEP(cur1.z) STEP(cur1.w)
        cur0 = n0; cur1 = n1;
    }
    #undef STEP

    // out[b] = dot(h, w_fc) + b_fc. Every lane holds h[l]; butterfly within
    // the 16-lane row (xor 8/4/2/1 never cross rows).
    float v = h * w_fc[l];
    v += __shfl_xor(v, 8);
    v += __shfl_xor(v, 4);
    v += __shfl_xor(v, 2);
    v += __shfl_xor(v, 1);
    if ((lane & 31) == 0) out[b] = v + b_fc[0];
}

extern "C" void kernel_launch(void* const* d_in, const int* in_sizes, int n_in,
                              void* d_out, int out_size, void* d_ws, size_t ws_size,
                              hipStream_t stream) {
    const float* x    = (const float*)d_in[0];
    const float* w_ih = (const float*)d_in[1];
    const float* w_hh = (const float*)d_in[2];
    const float* b_ih = (const float*)d_in[3];
    const float* b_hh = (const float*)d_in[4];
    const float* w_fc = (const float*)d_in[5];
    const float* b_fc = (const float*)d_in[6];
    float* out = (float*)d_out;

    const int B = out_size;                       // 4096
    const int threads = 256;
    const int blocks  = (B * 32) / threads;       // 512 blocks -> 2 waves/SIMD
    rnn_fused<<<blocks, threads, 0, stream>>>(x, w_ih, w_hh, b_ih, b_hh, w_fc, b_fc, out);
}

// Round 9
// 109.105 us; speedup vs baseline: 1.0121x; 1.0121x over previous
//
#include <hip/hip_runtime.h>

// RNN: h_t = tanh(x_t*w_ih + b_ih + b_hh + W_hh h_{t-1});  out = h_T . w_fc + b_fc
// B=4096, T=512, I=1, H=16, O=1.
//
// Round 8 = round 7 (verified PASS) minus per-step fat:
//  * Recurrence state is r = 1/(exp2(s')+1), with h = 1-2r FOLDED into the
//    weights: s = xw+b + SUM_k W[o][k] - 2*SUM_k W[o][k] r[k]. Rowsum goes
//    into the bias at setup; W_hh scaled by -2*C2LE. The final fmaf(-2,rc,1)
//    disappears from the serial chain (-1 inst, -1 dep level per step).
//  * Odd-row realign is a single in-place masked v_mov_b32_dpp
//    (update_dpp(old=P, src=P, ror8, row_mask 0xA)).
// Layout (verified rounds 2/7): 32 lanes per batch -> 2 waves/SIMD.
//   Row-even lane l: output o=l, term offsets 0..7 (plain fmaf r*w0 + 7 fused
//   DPP rotations), owns the x/bias/rowsum term. Row-odd lane l: output
//   o=(l+8)&15, same instruction rotations with odd-gathered weights = term
//   offsets 8..15, x/bias gated to 0. Masked ror8 realigns odd partials to
//   index (lane&15) (+8 mod 16 == xor 8, direction-independent);
//   permlane16_swap+add completes the 16-term dot in every lane.
// Direction-proofing: weights gathered by pushing the lane index through
// __builtin_amdgcn_update_dpp with ctrl 0x120+r — identical to the asm's
// row_ror:r — so the HW rotation convention cancels (verified r0/2/5/7).
// tanh: h = 1 - 2/(exp2(s')+1), s' = 2*log2(e)*s; prescale folded into
// weights/biases.

constexpr int T_STEPS = 512;
constexpr float C2LE = 2.8853900817779268f; // 2*log2(e)

#define DPP_CTRL_ROR(r) (0x120 + (r))
#define DPP_ROR_IDX(r, src) __builtin_amdgcn_update_dpp(0, (src), DPP_CTRL_ROR(r), 0xF, 0xF, false)
// In-place ror8 on 16-lane rows 1,3 only (row_mask 0xA); rows 0,2 keep old.
#define DPP_ROR8_ODDROWS(old_, src_) __builtin_amdgcn_update_dpp((old_), (src_), 0x128, 0xA, 0xF, false)

__device__ __forceinline__ float xor16_sum(float p) {
#if __has_builtin(__builtin_amdgcn_permlane16_swap)
    // a+b == p[lane] + p[lane^16] in every lane (VALU pipe, no DS).
    auto pr = __builtin_amdgcn_permlane16_swap((unsigned)__float_as_int(p),
                                               (unsigned)__float_as_int(p),
                                               false, false);
    return __int_as_float((int)pr[0]) + __int_as_float((int)pr[1]);
#else
    int o_ = __builtin_amdgcn_ds_swizzle(__float_as_int(p), 0x401F);
    return p + __int_as_float(o_);
#endif
}

__global__ __launch_bounds__(256) void rnn_fused(
    const float* __restrict__ x,
    const float* __restrict__ w_ih,
    const float* __restrict__ w_hh,
    const float* __restrict__ b_ih,
    const float* __restrict__ b_hh,
    const float* __restrict__ w_fc,
    const float* __restrict__ b_fc,
    float* __restrict__ out)
{
    const int tid     = blockIdx.x * blockDim.x + threadIdx.x;
    const int b       = tid >> 5;                 // batch element (32 lanes each)
    const int lane    = threadIdx.x & 63;         // wave lane
    const int l       = lane & 15;                // position within 16-lane row
    const int row_odd = (lane >> 4) & 1;          // odd row of the batch's pair
    const int o       = (l + (row_odd << 3)) & 15;// output unit this lane accumulates

    // Even row owns x/bias AND the h=1-2r constant part (full 16-term rowsum).
    float rowsum = 0.0f;
    {
        const int base = o << 4;
        #pragma unroll
        for (int k = 0; k < 16; ++k) rowsum += w_hh[base + k];
    }
    const float wihc  = row_odd ? 0.0f : w_ih[o] * C2LE;
    const float biasc = row_odd ? 0.0f : (b_ih[o] + b_hh[o] + rowsum) * C2LE;

    // Direction-proof weight gather; scale by -2*C2LE (the -2r fold).
    const float WS = -2.0f * C2LE;
    float wr[8];
    {
        const int base = o << 4;                  // w_hh row o (H x H row-major)
        wr[0] = w_hh[base + l] * WS;              // r=0: own-lane term
        #define WSETUP(r) { int s_ = DPP_ROR_IDX(r, l); wr[r] = w_hh[base + s_] * WS; }
        WSETUP(1) WSETUP(2) WSETUP(3) WSETUP(4) WSETUP(5) WSETUP(6) WSETUP(7)
        #undef WSETUP
    }
    const float w0 = wr[0], w1 = wr[1], w2 = wr[2], w3 = wr[3];
    const float w4 = wr[4], w5 = wr[5], w6 = wr[6], w7 = wr[7];

    const float* xb = x + ((size_t)b << 9);       // x[b,:,0], 512 floats, 16B aligned
    float r_ = 0.5f;                              // h0 = 0  ->  r0 = 0.5

    // One timestep, ~17 issued insts. The two C fmafs between the v_rcp write
    // of r_ and the first DPP read of it provide 2 slots; s_nop 1 adds the
    // remaining margin for the trans-write -> DPP-read hazard.
    #define STEP(xval) {                                                       \
        float p0 = fmaf((xval), wihc, biasc);                                  \
        p0 = fmaf(r_, w0, p0);                                                 \
        float p1;                                                              \
        asm volatile(                                                          \
          "s_nop 1\n\t"                                                        \
          "v_mul_f32_dpp  %0, %2, %3 row_ror:1 row_mask:0xf bank_mask:0xf\n\t" \
          "v_fmac_f32_dpp %1, %2, %4 row_ror:2 row_mask:0xf bank_mask:0xf\n\t" \
          "v_fmac_f32_dpp %0, %2, %5 row_ror:3 row_mask:0xf bank_mask:0xf\n\t" \
          "v_fmac_f32_dpp %1, %2, %6 row_ror:4 row_mask:0xf bank_mask:0xf\n\t" \
          "v_fmac_f32_dpp %0, %2, %7 row_ror:5 row_mask:0xf bank_mask:0xf\n\t" \
          "v_fmac_f32_dpp %1, %2, %8 row_ror:6 row_mask:0xf bank_mask:0xf\n\t" \
          "v_fmac_f32_dpp %0, %2, %9 row_ror:7 row_mask:0xf bank_mask:0xf"     \
          : "=&v"(p1), "+v"(p0)                                                \
          : "v"(r_), "v"(w1), "v"(w2), "v"(w3), "v"(w4), "v"(w5), "v"(w6),     \
            "v"(w7));                                                          \
        float P = p0 + p1;                                                     \
        P = __int_as_float(DPP_ROR8_ODDROWS(__float_as_int(P),                 \
                                            __float_as_int(P)));               \
        const float s_ = xor16_sum(P);    /* full scaled dot, every lane */    \
        const float e_ = __builtin_amdgcn_exp2f(s_);                           \
        r_ = __builtin_amdgcn_rcpf(e_ + 1.0f);  /* state: r = (1-h)/2 */       \
    }

    // 8 steps/iter; next x block prefetched as 2x float4 (L1-resident,
    // 32 lanes same address -> broadcast).
    float4 cur0 = *reinterpret_cast<const float4*>(xb);
    float4 cur1 = *reinterpret_cast<const float4*>(xb + 4);
    #pragma unroll 1
    for (int tb = 0; tb < T_STEPS; tb += 8) {
        const int nxt = (tb + 8 < T_STEPS) ? (tb + 8) : 0;  // last iter: dummy
        const float4 n0 = *reinterpret_cast<const float4*>(xb + nxt);
        const float4 n1 = *reinterpret_cast<const float4*>(xb + nxt + 4);
        STEP(cur0.x) STEP(cur0.y) STEP(cur0.z) STEP(cur0.w)
        STEP(cur1.x) STEP(cur1.y) STEP(cur1.z) STEP(cur1.w)
        cur0 = n0; cur1 = n1;
    }
    #undef STEP

    // Reconstruct h = 1 - 2r once; out[b] = dot(h, w_fc) + b_fc.
    const float h = fmaf(-2.0f, r_, 1.0f);        // every lane: h[lane&15]
    float v = h * w_fc[l];
    v += __shfl_xor(v, 8);
    v += __shfl_xor(v, 4);
    v += __shfl_xor(v, 2);
    v += __shfl_xor(v, 1);
    if ((lane & 31) == 0) out[b] = v + b_fc[0];
}

extern "C" void kernel_launch(void* const* d_in, const int* in_sizes, int n_in,
                              void* d_out, int out_size, void* d_ws, size_t ws_size,
                              hipStream_t stream) {
    const float* x    = (const float*)d_in[0];
    const float* w_ih = (const float*)d_in[1];
    const float* w_hh = (const float*)d_in[2];
    const float* b_ih = (const float*)d_in[3];
    const float* b_hh = (const float*)d_in[4];
    const float* w_fc = (const float*)d_in[5];
    const float* b_fc = (const float*)d_in[6];
    float* out = (float*)d_out;

    const int B = out_size;                       // 4096
    const int threads = 256;
    const int blocks  = (B * 32) / threads;       // 512 blocks -> 2 waves/SIMD
    rnn_fused<<<blocks, threads, 0, stream>>>(x, w_ih, w_hh, b_ih, b_hh, w_fc, b_fc, out);
}

// Round 12
// 101.444 us; speedup vs baseline: 1.0885x; 1.0755x over previous
//
#include <hip/hip_runtime.h>

// RNN: h_t = tanh(x_t*w_ih + b_ih + b_hh + W_hh h_{t-1});  out = h_T . w_fc + b_fc
// B=4096, T=512, I=1, H=16, O=1.
//
// Round 9: minimum-dependency-depth step on the 16-lane layout.
//   Problem has exactly 4096 serial chains on 1024 SIMDs -> 4 chains/SIMD max;
//   rounds 5/7/8 proved all layouts are chain-latency-bound, so this round
//   shortens the chain: 16-lane layout (no cross-row combine levels, r5
//   verified) + r-state fold (no final fmaf level, r8 verified) + 8
//   accumulators with depth-2 DPP chains + 3-level add tree (new; replaces
//   r5's depth-4 chains + 2-level tree).
//   Chain/step: snop + 2 DPP + 3 adds + exp + add + rcp  (~8 levels, 2 trans)
//   vs r5's ~11 levels and r8's ~14.
//
// r-state: r = 1/(exp2(s')+1), h = 1-2r folded into weights:
//   s' = C2LE*(x*wih + b + SUM_k W[o][k]) - 2*C2LE*SUM_k W[o][k]*r[k]
//   rowsum into bias at setup; W_hh scaled by -2*C2LE; h reconstructed once
//   in the epilogue. h0 = 0 -> r0 = 0.5.
// Direction-proofing (verified r0/2/5/7/8): weights gathered by pushing the
// lane index through __builtin_amdgcn_update_dpp with ctrl 0x120+r — the same
// ctrl the asm's row_ror:r encodes — so the HW rotation convention cancels.
// Hazard: VALU-write(r_) -> DPP-read(r_) needs 2 wait states; the fmaf(r_,w0)
// between rcp and the asm plus s_nop 1 inside it covers the worst case even
// if the compiler hoists the independent x-seed fmaf.

constexpr int T_STEPS = 512;
constexpr float C2LE = 2.8853900817779268f; // 2*log2(e)

#define DPP_CTRL_ROR(r) (0x120 + (r))
#define DPP_ROR_IDX(r, src) __builtin_amdgcn_update_dpp(0, (src), DPP_CTRL_ROR(r), 0xF, 0xF, false)

__global__ __launch_bounds__(256) void rnn_fused(
    const float* __restrict__ x,
    const float* __restrict__ w_ih,
    const float* __restrict__ w_hh,
    const float* __restrict__ b_ih,
    const float* __restrict__ b_hh,
    const float* __restrict__ w_fc,
    const float* __restrict__ b_fc,
    float* __restrict__ out)
{
    const int tid = blockIdx.x * blockDim.x + threadIdx.x;
    const int b   = tid >> 4;   // batch element (16 lanes each)
    const int me  = tid & 15;   // hidden unit owned by this lane

    // Bias carries the h = 1-2r constant part: full 16-term rowsum.
    float rowsum = 0.0f;
    {
        const int base = me << 4;
        #pragma unroll
        for (int k = 0; k < 16; ++k) rowsum += w_hh[base + k];
    }
    const float wihc  = w_ih[me] * C2LE;
    const float biasc = (b_ih[me] + b_hh[me] + rowsum) * C2LE;

    // Direction-proof weight gather; scale by -2*C2LE (the -2r fold).
    const float WS = -2.0f * C2LE;
    float wr[16];
    {
        const int base = me << 4;            // w_hh row 'me' (H x H row-major)
        wr[0] = w_hh[base + me] * WS;
        #define WSETUP(r) { int s_ = DPP_ROR_IDX(r, me); wr[r] = w_hh[base + s_] * WS; }
        WSETUP(1)  WSETUP(2)  WSETUP(3)  WSETUP(4)  WSETUP(5)
        WSETUP(6)  WSETUP(7)  WSETUP(8)  WSETUP(9)  WSETUP(10)
        WSETUP(11) WSETUP(12) WSETUP(13) WSETUP(14) WSETUP(15)
        #undef WSETUP
    }
    const float w0 = wr[0],  w1 = wr[1],  w2 = wr[2],  w3 = wr[3];
    const float w4 = wr[4],  w5 = wr[5],  w6 = wr[6],  w7 = wr[7];
    const float w8 = wr[8],  w9 = wr[9],  w10 = wr[10], w11 = wr[11];
    const float w12 = wr[12], w13 = wr[13], w14 = wr[14], w15 = wr[15];

    const float* xb = x + ((size_t)b << 9);  // x[b,:,0], 512 floats, 16B aligned
    float r_ = 0.5f;                         // h0 = 0 -> r0 = 0.5

    // One timestep: 8 accumulators, each a depth-2 chain (mul/fmac + fmac),
    // then a 3-level add tree -> exp2 -> +1 -> rcp. ~27 issued insts, ~8
    // dependency levels.
    #define STEP(xval) {                                                        \
        float A0 = fmaf((xval), wihc, biasc);                                   \
        A0 = fmaf(r_, w0, A0);                                                  \
        float A1, A2, A3, A4, A5, A6, A7;                                       \
        asm volatile(                                                           \
          "s_nop 1\n\t"                                                         \
          "v_mul_f32_dpp  %0, %8, %10 row_ror:1 row_mask:0xf bank_mask:0xf\n\t" \
          "v_mul_f32_dpp  %1, %8, %11 row_ror:2 row_mask:0xf bank_mask:0xf\n\t" \
          "v_mul_f32_dpp  %2, %8, %12 row_ror:3 row_mask:0xf bank_mask:0xf\n\t" \
          "v_mul_f32_dpp  %3, %8, %13 row_ror:4 row_mask:0xf bank_mask:0xf\n\t" \
          "v_mul_f32_dpp  %4, %8, %14 row_ror:5 row_mask:0xf bank_mask:0xf\n\t" \
          "v_mul_f32_dpp  %5, %8, %15 row_ror:6 row_mask:0xf bank_mask:0xf\n\t" \
          "v_mul_f32_dpp  %6, %8, %16 row_ror:7 row_mask:0xf bank_mask:0xf\n\t" \
          "v_fmac_f32_dpp %7, %8, %17 row_ror:8 row_mask:0xf bank_mask:0xf\n\t" \
          "v_fmac_f32_dpp %0, %8, %18 row_ror:9 row_mask:0xf bank_mask:0xf\n\t" \
          "v_fmac_f32_dpp %1, %8, %19 row_ror:10 row_mask:0xf bank_mask:0xf\n\t"\
          "v_fmac_f32_dpp %2, %8, %20 row_ror:11 row_mask:0xf bank_mask:0xf\n\t"\
          "v_fmac_f32_dpp %3, %8, %21 row_ror:12 row_mask:0xf bank_mask:0xf\n\t"\
          "v_fmac_f32_dpp %4, %8, %22 row_ror:13 row_mask:0xf bank_mask:0xf\n\t"\
          "v_fmac_f32_dpp %5, %8, %23 row_ror:14 row_mask:0xf bank_mask:0xf\n\t"\
          "v_fmac_f32_dpp %6, %8, %24 row_ror:15 row_mask:0xf bank_mask:0xf"    \
          : "=&v"(A1), "=&v"(A2), "=&v"(A3), "=&v"(A4),                         \
            "=&v"(A5), "=&v"(A6), "=&v"(A7), "+v"(A0)                           \
          : "v"(r_), "v"(w0) /* unused, keeps numbering sane */,                \
            "v"(w1), "v"(w2), "v"(w3), "v"(w4), "v"(w5), "v"(w6), "v"(w7),      \
            "v"(w8), "v"(w9), "v"(w10), "v"(w11), "v"(w12), "v"(w13),           \
            "v"(w14), "v"(w15));                                                \
        const float t0 = A0 + A1, t1 = A2 + A3, t2 = A4 + A5, t3 = A6 + A7;     \
        const float u0 = t0 + t1, u1 = t2 + t3;                                 \
        const float s_ = u0 + u1;                                               \
        const float e_ = __builtin_amdgcn_exp2f(s_);                            \
        r_ = __builtin_amdgcn_rcpf(e_ + 1.0f);  /* state: r = (1-h)/2 */        \
    }

    // 8 steps/iter; next x block prefetched as 2x float4 (L1-resident,
    // 16 lanes same address -> broadcast).
    float4 cur0 = *reinterpret_cast<const float4*>(xb);
    float4 cur1 = *reinterpret_cast<const float4*>(xb + 4);
    #pragma unroll 1
    for (int tb = 0; tb < T_STEPS; tb += 8) {
        const int nxt = (tb + 8 < T_STEPS) ? (tb + 8) : 0;  // last iter: dummy
        const float4 n0 = *reinterpret_cast<const float4*>(xb + nxt);
        const float4 n1 = *reinterpret_cast<const float4*>(xb + nxt + 4);
        STEP(cur0.x) STEP(cur0.y) STEP(cur0.z) STEP(cur0.w)
        STEP(cur1.x) STEP(cur1.y) STEP(cur1.z) STEP(cur1.w)
        cur0 = n0; cur1 = n1;
    }
    #undef STEP

    // Reconstruct h = 1 - 2r once; out[b] = dot(h, w_fc) + b_fc.
    const float h = fmaf(-2.0f, r_, 1.0f);
    float v = h * w_fc[me];
    v += __shfl_xor(v, 8);
    v += __shfl_xor(v, 4);
    v += __shfl_xor(v, 2);
    v += __shfl_xor(v, 1);
    if (me == 0) out[b] = v + b_fc[0];
}

extern "C" void kernel_launch(void* const* d_in, const int* in_sizes, int n_in,
                              void* d_out, int out_size, void* d_ws, size_t ws_size,
                              hipStream_t stream) {
    const float* x    = (const float*)d_in[0];
    const float* w_ih = (const float*)d_in[1];
    const float* w_hh = (const float*)d_in[2];
    const float* b_ih = (const float*)d_in[3];
    const float* b_hh = (const float*)d_in[4];
    const float* w_fc = (const float*)d_in[5];
    const float* b_fc = (const float*)d_in[6];
    float* out = (float*)d_out;

    const int B = out_size;                  // 4096
    const int threads = 256;
    const int blocks  = (B * 16) / threads;  // 256 blocks -> 1/CU, 1 wave/SIMD
    rnn_fused<<<blocks, threads, 0, stream>>>(x, w_ih, w_hh, b_ih, b_hh, w_fc, b_fc, out);
}